// Round 16
// baseline (156.446 us; speedup 1.0000x reference)
//
#include <hip/hip_runtime.h>
#include <hip/hip_bf16.h>

#define T_IN   16
#define T_OUT  25
#define BHERO  4096
#define K_NBR  32
#define N_NBR  (BHERO * K_NBR)
#define ENC    64
#define DEC    128
#define DYN    32
#define EMB    32
#define HEROES 8          // real heroes/WG; MFMA A-rows 8-15 stay ZERO (outputs ignored)

#define EMROW  40         // emb row: 32 bf16 + 8 pad (80 B)
#define HROW   72         // encoder h row: 64 bf16 + 8 pad (144 B)
#define RROW   40         // rela row: 32 bf16 + 8 pad (80 B)
#define DROW   136        // decoder h row: 128 bf16 + 8 pad (272 B)

// ---- LDS layout (flat; 46.2 KB -> 2 WGs/CU) ----
#define OFF_HRING  20480
#define OFF_RELA   25088
#define OFF_PMAX   27648
#define OFF_RINGD  31744
#define OFF_ENC    40448
#define OFF_WOP    44800
#define OFF_WIP    45824
#define OFF_BIP    46080
#define OFF_BOP    46208
#define LDS_TOTAL  46216

#define L2E 1.44269504f   // log2(e); gate pre-scales fold the exp-arg mul into W/b

typedef __attribute__((ext_vector_type(8))) short bf16x8;   // 8 bf16 in 4 VGPRs
typedef __attribute__((ext_vector_type(4))) float f32x4;    // MFMA 16x16 C/D frag

__device__ __forceinline__ float lrelu(float x) { return x >= 0.f ? x : 0.1f * x; }
__device__ __forceinline__ float rcpf(float x)  { return __builtin_amdgcn_rcpf(x); }
__device__ __forceinline__ float ex2(float x)   { return __builtin_amdgcn_exp2f(x); }
__device__ __forceinline__ unsigned pk2(float lo, float hi) {
    __hip_bfloat162 p = __float22bfloat162_rn(make_float2(lo, hi));
    unsigned u; __builtin_memcpy(&u, &p, 4); return u;
}
__device__ __forceinline__ short f2bf16(float x) {
    return (short)(pk2(x, 0.f) & 0xFFFF);
}
__device__ __forceinline__ bf16x8 mk_frag(float4 f0, float4 f1) {
    uint4 v = { pk2(f0.x, f0.y), pk2(f0.z, f0.w), pk2(f1.x, f1.y), pk2(f1.z, f1.w) };
    bf16x8 r; __builtin_memcpy(&r, &v, 16); return r;
}
__device__ __forceinline__ bf16x8 mk_frag_s(float4 f0, float4 f1, float s) {
    uint4 v = { pk2(f0.x*s, f0.y*s), pk2(f0.z*s, f0.w*s), pk2(f1.x*s, f1.y*s), pk2(f1.z*s, f1.w*s) };
    bf16x8 r; __builtin_memcpy(&r, &v, 16); return r;
}
__device__ __forceinline__ float bf2f(short s) {
    return __uint_as_float(((unsigned)(unsigned short)s) << 16);
}
// Fused LSTM cell update on PRESCALED gates (i,f,o x L2E; g x 2*L2E). 5 exp + 3 rcp.
__device__ __forceinline__ float2 cell_update(float gi, float gf, float gg, float go, float c) {
    float ea = ex2(-gi);
    float ef = ex2(-gf);
    float eb = ex2(-gg);
    float eo = ex2(-go);
    float ff = rcpf(1.f + ef);
    float ig = (1.f - eb) * rcpf((1.f + ea) * (1.f + eb));
    float cc = fmaf(ff, c, ig);
    float ec = ex2(-2.f * L2E * cc);
    float h  = (1.f - ec) * rcpf((1.f + eo) * (1.f + ec));
    return make_float2(h, cc);
}

// ====== fused highwayNet fwd: 512 WGs x 512 threads (8 waves), 8 heroes/WG, 2 WGs/CU ======
// Per-wave decoder code identical to R13 (1 unit-block, BfD=64 VGPRs, ~88 total).
// M=16 MFMA tiles; A-rows 8-15 zero; nonlin/stores masked to lg<2.
__global__ __launch_bounds__(512, 4) void highway_fused(
    const float* __restrict__ hist,  const float* __restrict__ nbrs,
    const float* __restrict__ Wip,   const float* __restrict__ bip,
    const float* __restrict__ WihE,  const float* __restrict__ WhhE,
    const float* __restrict__ bihE,  const float* __restrict__ bhhE,
    const float* __restrict__ Wdyn,  const float* __restrict__ bdyn,
    const float* __restrict__ Wnbr,  const float* __restrict__ bnbr,
    const float* __restrict__ WihD,  const float* __restrict__ WhhD,
    const float* __restrict__ bihD,  const float* __restrict__ bhhD,
    const float* __restrict__ Wop,   const float* __restrict__ bop,
    const int*   __restrict__ seg,
    float* __restrict__ fut)                        // [T_OUT][BHERO][2]
{
    __shared__ __align__(16) char lds_raw[LDS_TOTAL];
    auto embs   = (short (*)[16][EMROW])  lds_raw;                  // [16][16][EMROW]
    auto hringE = (short (*)[16][HROW])  (lds_raw + OFF_HRING);     // [2][16][HROW]
    auto rela2  = (short (*)[16][RROW])  (lds_raw + OFF_RELA);      // [2][16][RROW]
    auto pmax   = (float (*)[ENC])       (lds_raw + OFF_PMAX);      // [16][64]
    auto ringD  = (short (*)[16][DROW])  (lds_raw + OFF_RINGD);     // [2][16][DROW]
    auto enc_s  = (float (*)[68])        (lds_raw + OFF_ENC);       // [16][68]
    auto wop_s  = (float (*)[DEC])       (lds_raw + OFF_WOP);       // [2][128]
    auto wip_s  = (float (*)[2])         (lds_raw + OFF_WIP);       // [32][2]
    auto bip_s  = (float*)               (lds_raw + OFF_BIP);       // [32]
    auto bop_s  = (float*)               (lds_raw + OFF_BOP);       // [2]

    const int b0  = blockIdx.x * HEROES;
    const int n0  = blockIdx.x * (HEROES * K_NBR);  // 256 nbr rows per WG
    const int tid = threadIdx.x;
    const int w = tid >> 6, l = tid & 63, r = l & 15, lg = l >> 4;
    const bool valid = (lg < 2);                    // A-rows 0-7 = real heroes

    // ---------------- P0: consts + zero all M=16 buffers (rows 8-15 stay 0 forever) ----------------
    if (tid < EMB) {
        wip_s[tid][0] = Wip[2 * tid];
        wip_s[tid][1] = Wip[2 * tid + 1];
        bip_s[tid]    = bip[tid];
    }
    if (tid < 2 * DEC) wop_s[tid >> 7][tid & 127] = Wop[tid];
    if (tid < 2)       bop_s[tid] = bop[tid];
    for (int i = tid; i < 16 * 16 * EMROW; i += 512) ((short*)embs)[i]   = 0;
    for (int i = tid; i < 2 * 16 * HROW;   i += 512) ((short*)hringE)[i] = 0;
    for (int i = tid; i < 2 * 16 * DROW;   i += 512) ((short*)ringD)[i]  = 0;
    for (int i = tid; i < 16 * 68;         i += 512) ((float*)enc_s)[i]  = 0.f;

    // encoder B-frags (waves 0-3, prescaled) / nbr B-frag (waves 4-7: wave i -> col-tile i)
    bf16x8 BfE[4][3];
    float  biasE[4];
    bf16x8 BfN;
    float  biasn = 0.f;
    if (tid < 256) {
        #pragma unroll
        for (int j = 0; j < 4; ++j) {
            const float sj  = (j == 2) ? (2.f * L2E) : L2E;
            const int   col = j * ENC + w * 16 + r;
            biasE[j] = (bihE[col] + bhhE[col]) * sj;
            #pragma unroll
            for (int c = 0; c < 3; ++c) {
                const float* src = (c == 0) ? (WihE + (size_t)col * EMB + 8 * lg)
                                            : (WhhE + (size_t)col * ENC + (c - 1) * 32 + 8 * lg);
                BfE[j][c] = mk_frag_s(*(const float4*)src, *(const float4*)(src + 4), sj);
            }
        }
    } else {
        const int col = (w - 4) * 16 + r;
        biasn = bnbr[col];
        const float* src = Wnbr + (size_t)col * (2 * T_IN) + 8 * lg;
        BfN = mk_frag(*(const float4*)src, *(const float4*)(src + 4));
    }
    __syncthreads();                                // consts + zeros ready

    // ---------------- P1: emb prefill (all) + rela tile 0 (waves 4-7) ----------------
    {   // 128 (t,m) tasks x 4 quarter-rows = 512
        const int task = tid >> 2;
        const int t = task >> 3, m = task & 7;
        const int j0 = (tid & 3) * 8;
        float2 hv = *(const float2*)&hist[((size_t)t * BHERO + b0 + m) * 2];
        float e[8];
        #pragma unroll
        for (int q = 0; q < 8; ++q) {
            int j = j0 + q;
            e[q] = lrelu(hv.x * wip_s[j][0] + hv.y * wip_s[j][1] + bip_s[j]);
        }
        uint4 v = { pk2(e[0],e[1]), pk2(e[2],e[3]), pk2(e[4],e[5]), pk2(e[6],e[7]) };
        __builtin_memcpy(&embs[t][m][j0], &v, 16);
    }
    if (tid >= 256) {                               // rela tile 0: 16 rows x 16 ts
        const int x = tid - 256, nloc = x & 15, ts = x >> 4;
        const int hb = seg[n0 + nloc];
        float2 h0 = *(const float2*)&hist[((size_t)ts * BHERO + hb) * 2];
        float2 v0 = *(const float2*)&nbrs[((size_t)ts * N_NBR + n0 + nloc) * 2];
        ((unsigned*)&rela2[0][nloc][0])[ts] = pk2(h0.x - v0.x, h0.y - v0.y);
    }
    f32x4 cstE = {0.f, 0.f, 0.f, 0.f};              // valid lanes: hero 4*lg+q, unit w*16+r
    __syncthreads();                                // emb + rela tile 0 ready

    // ---------------- P2: encoder LSTM (waves 0-3) || nbr stage+GEMM (waves 4-7) ----------------
    #pragma unroll 1
    for (int t = 0; t < T_IN; ++t) {
        const int cur = t & 1, nxt = cur ^ 1;
        if (tid < 256) {
            bf16x8 a0 = *(const bf16x8*)&embs[t][r][8 * lg];
            bf16x8 a1 = *(const bf16x8*)&hringE[cur][r][8 * lg];
            bf16x8 a2 = *(const bf16x8*)&hringE[cur][r][32 + 8 * lg];
            f32x4 acc[4];
            #pragma unroll
            for (int j = 0; j < 4; ++j) {
                f32x4 aA = (f32x4){biasE[j], biasE[j], biasE[j], biasE[j]};
                f32x4 aB = (f32x4){0.f, 0.f, 0.f, 0.f};
                aA = __builtin_amdgcn_mfma_f32_16x16x32_bf16(a0, BfE[j][0], aA, 0, 0, 0);
                aB = __builtin_amdgcn_mfma_f32_16x16x32_bf16(a1, BfE[j][1], aB, 0, 0, 0);
                aA = __builtin_amdgcn_mfma_f32_16x16x32_bf16(a2, BfE[j][2], aA, 0, 0, 0);
                acc[j] = aA + aB;
            }
            if (valid) {
                #pragma unroll
                for (int q = 0; q < 4; ++q) {
                    float2 hc = cell_update(acc[0][q], acc[1][q], acc[2][q], acc[3][q], cstE[q]);
                    cstE[q] = hc.y;
                    hringE[nxt][4 * lg + q][w * 16 + r] = f2bf16(hc.x);
                }
            }
        } else {
            const int x = tid - 256, nloc = x & 15, ts = x >> 4;
            // issue tile t+1 loads first (consumed after the GEMM below)
            float2 h0 = {}, v0 = {};
            if (t < T_IN - 1) {
                const int n  = 16 * (t + 1) + nloc;
                const int hb = seg[n0 + n];
                h0 = *(const float2*)&hist[((size_t)ts * BHERO + hb) * 2];
                v0 = *(const float2*)&nbrs[((size_t)ts * N_NBR + n0 + n) * 2];
            }
            // GEMM tile t: wave i = w-4 -> col-tile i (16 real nbr rows, no waste)
            bf16x8 a = *(const bf16x8*)&rela2[cur][r][8 * lg];
            f32x4 accN = {biasn, biasn, biasn, biasn};
            accN = __builtin_amdgcn_mfma_f32_16x16x32_bf16(a, BfN, accN, 0, 0, 0);
            float m4 = fmaxf(fmaxf(accN[0], accN[1]), fmaxf(accN[2], accN[3]));
            m4 = fmaxf(m4, __shfl_xor(m4, 16));
            m4 = fmaxf(m4, __shfl_xor(m4, 32));
            if (l < 16) pmax[t][(w - 4) * 16 + r] = m4;
            if (t < T_IN - 1)
                ((unsigned*)&rela2[nxt][nloc][0])[ts] = pk2(h0.x - v0.x, h0.y - v0.y);
        }
        __syncthreads();                            // h(t+1) + tile t+1 + pmax t ready
    }

    // ---------------- P3: enc_s = [hist_e | scene_d] (rows 0-7; 8-15 stay 0) ----------------
    {
        const int m = tid >> 6, col = tid & 63;     // 512 tasks exactly
        const float* wd = Wdyn + (size_t)(col & 31) * ENC;
        float a = bdyn[col & 31];
        if (col < 32) {
            const short* hp = &hringE[0][m][0];     // final h in slab 0 after 16 flips
            #pragma unroll
            for (int kb = 0; kb < 8; ++kb) {
                bf16x8 hv = *(const bf16x8*)(hp + kb * 8);
                #pragma unroll
                for (int e = 0; e < 8; ++e)
                    a = fmaf(bf2f(hv[e]), wd[kb * 8 + e], a);
            }
        } else {
            #pragma unroll
            for (int kb = 0; kb < 16; ++kb) {
                float4 p0 = *(const float4*)&pmax[2 * m][kb * 4];
                float4 p1 = *(const float4*)&pmax[2 * m + 1][kb * 4];
                a = fmaf(lrelu(fmaxf(p0.x, p1.x)), wd[kb * 4 + 0], a);
                a = fmaf(lrelu(fmaxf(p0.y, p1.y)), wd[kb * 4 + 1], a);
                a = fmaf(lrelu(fmaxf(p0.z, p1.z)), wd[kb * 4 + 2], a);
                a = fmaf(lrelu(fmaxf(p0.w, p1.w)), wd[kb * 4 + 3], a);
            }
        }
        enc_s[m][col] = lrelu(a);
    }
    __syncthreads();                                // enc_s ready (ringD zeroed in P0)

    // ---------------- P4: decoder (R13 per-wave structure) + inline output head ----------------
    const int u0 = w * 16;
    bf16x8 BfD[4][4];                               // 64 VGPRs
    float  biasD[4];
    #pragma unroll
    for (int j = 0; j < 4; ++j) {
        const float sj  = (j == 2) ? (2.f * L2E) : L2E;
        const int   col = j * DEC + u0 + r;
        biasD[j] = (bihD[col] + bhhD[col]) * sj;
        #pragma unroll
        for (int c = 0; c < 4; ++c) {
            const float* src = WhhD + (size_t)col * DEC + c * 32 + 8 * lg;
            BfD[j][c] = mk_frag_s(*(const float4*)src, *(const float4*)(src + 4), sj);
        }
    }
    f32x4 xwf[4];
    {
        bf16x8 aE[2];
        #pragma unroll
        for (int c = 0; c < 2; ++c) {
            float4 f0 = *(const float4*)&enc_s[r][c * 32 + 8 * lg];
            float4 f1 = *(const float4*)&enc_s[r][c * 32 + 8 * lg + 4];
            aE[c] = mk_frag(f0, f1);
        }
        #pragma unroll
        for (int j = 0; j < 4; ++j) {
            const float sj  = (j == 2) ? (2.f * L2E) : L2E;
            const int   col = j * DEC + u0 + r;
            f32x4 a = {biasD[j], biasD[j], biasD[j], biasD[j]};
            #pragma unroll
            for (int c = 0; c < 2; ++c) {
                const float* src = WihD + (size_t)col * (2 * DYN) + c * 32 + 8 * lg;
                a = __builtin_amdgcn_mfma_f32_16x16x32_bf16(
                        aE[c], mk_frag_s(*(const float4*)src, *(const float4*)(src + 4), sj),
                        a, 0, 0, 0);
            }
            xwf[j] = a;
        }
    }

    f32x4 cst = {0.f, 0.f, 0.f, 0.f};
    #pragma unroll 1
    for (int t = 0; t < T_OUT; ++t) {
        const int cur = t & 1, nxt = cur ^ 1;
        const short* rp = &ringD[cur][r][0];
        bf16x8 a_[4];
        #pragma unroll
        for (int c = 0; c < 4; ++c)
            a_[c] = *(const bf16x8*)(rp + (4 * c + lg) * 8);
        f32x4 acc[4];
        #pragma unroll
        for (int j = 0; j < 4; ++j) {
            f32x4 aA = xwf[j];
            f32x4 aB = (f32x4){0.f, 0.f, 0.f, 0.f};
            aA = __builtin_amdgcn_mfma_f32_16x16x32_bf16(a_[0], BfD[j][0], aA, 0, 0, 0);
            aB = __builtin_amdgcn_mfma_f32_16x16x32_bf16(a_[1], BfD[j][1], aB, 0, 0, 0);
            aA = __builtin_amdgcn_mfma_f32_16x16x32_bf16(a_[2], BfD[j][2], aA, 0, 0, 0);
            aB = __builtin_amdgcn_mfma_f32_16x16x32_bf16(a_[3], BfD[j][3], aB, 0, 0, 0);
            acc[j] = aA + aB;
        }
        // inline output head: a_ holds h entering step t = h_dec(t-1) -> fut[t-1]
        if (t >= 1 && w == ((t - 1) & 7)) {
            f32x4 accO = {0.f, 0.f, 0.f, 0.f};
            #pragma unroll
            for (int c = 0; c < 4; ++c) {
                bf16x8 bo = (bf16x8){0, 0, 0, 0, 0, 0, 0, 0};
                if (r < 2) {
                    float4 f0 = *(const float4*)&wop_s[r][c * 32 + 8 * lg];
                    float4 f1 = *(const float4*)&wop_s[r][c * 32 + 8 * lg + 4];
                    bo = mk_frag(f0, f1);
                }
                accO = __builtin_amdgcn_mfma_f32_16x16x32_bf16(a_[c], bo, accO, 0, 0, 0);
            }
            if (r < 2 && lg < 2) {
                #pragma unroll
                for (int q = 0; q < 4; ++q)
                    fut[((size_t)(t - 1) * BHERO + b0 + 4 * lg + q) * 2 + r] = accO[q] + bop_s[r];
            }
        }
        if (valid) {
            #pragma unroll
            for (int q = 0; q < 4; ++q) {
                float2 hc = cell_update(acc[0][q], acc[1][q], acc[2][q], acc[3][q], cst[q]);
                cst[q] = hc.y;
                ringD[nxt][4 * lg + q][u0 + r] = f2bf16(hc.x);
            }
        }
        __syncthreads();                            // h(t+1) ready (slab nxt last read 2 iters ago)
    }

    // ---------------- P5: last output (t = T_OUT-1) from ringD[T_OUT&1] ----------------
    if (w == ((T_OUT - 1) & 7)) {
        const short* rp = &ringD[T_OUT & 1][r][0];
        bf16x8 a_[4];
        #pragma unroll
        for (int c = 0; c < 4; ++c)
            a_[c] = *(const bf16x8*)(rp + (4 * c + lg) * 8);
        f32x4 accO = {0.f, 0.f, 0.f, 0.f};
        #pragma unroll
        for (int c = 0; c < 4; ++c) {
            bf16x8 bo = (bf16x8){0, 0, 0, 0, 0, 0, 0, 0};
            if (r < 2) {
                float4 f0 = *(const float4*)&wop_s[r][c * 32 + 8 * lg];
                float4 f1 = *(const float4*)&wop_s[r][c * 32 + 8 * lg + 4];
                bo = mk_frag(f0, f1);
            }
            accO = __builtin_amdgcn_mfma_f32_16x16x32_bf16(a_[c], bo, accO, 0, 0, 0);
        }
        if (r < 2 && lg < 2) {
            #pragma unroll
            for (int q = 0; q < 4; ++q)
                fut[((size_t)(T_OUT - 1) * BHERO + b0 + 4 * lg + q) * 2 + r] = accO[q] + bop_s[r];
        }
    }
}

extern "C" void kernel_launch(void* const* d_in, const int* in_sizes, int n_in,
                              void* d_out, int out_size, void* d_ws, size_t ws_size,
                              hipStream_t stream) {
    (void)d_ws; (void)ws_size; (void)in_sizes; (void)n_in; (void)out_size;
    const float* hist  = (const float*)d_in[0];
    const float* nbrs  = (const float*)d_in[1];
    const float* Wip   = (const float*)d_in[2];
    const float* bip   = (const float*)d_in[3];
    const float* Wih_e = (const float*)d_in[4];
    const float* Whh_e = (const float*)d_in[5];
    const float* bih_e = (const float*)d_in[6];
    const float* bhh_e = (const float*)d_in[7];
    const float* Wdyn  = (const float*)d_in[8];
    const float* bdyn  = (const float*)d_in[9];
    const float* Wnbr  = (const float*)d_in[10];
    const float* bnbr  = (const float*)d_in[11];
    const float* Wih_d = (const float*)d_in[12];
    const float* Whh_d = (const float*)d_in[13];
    const float* bih_d = (const float*)d_in[14];
    const float* bhh_d = (const float*)d_in[15];
    const float* Wop   = (const float*)d_in[16];
    const float* bop   = (const float*)d_in[17];
    const int*   seg   = (const int*)d_in[18];
    float* fut = (float*)d_out;

    hipLaunchKernelGGL(highway_fused, dim3(BHERO / HEROES), dim3(512), 0, stream,
                       hist, nbrs, Wip, bip, Wih_e, Whh_e, bih_e, bhh_e, Wdyn, bdyn,
                       Wnbr, bnbr, Wih_d, Whh_d, bih_d, bhh_d, Wop, bop, seg, fut);
}

// Round 17
// 61.741 us; speedup vs baseline: 2.5339x; 2.5339x over previous
//
#include <hip/hip_runtime.h>
#include <hip/hip_bf16.h>

#define T_IN   16
#define T_OUT  25
#define BHERO  4096
#define K_NBR  32
#define N_NBR  (BHERO * K_NBR)
#define ENC    64
#define DEC    128
#define DYN    32
#define EMB    32

#define EROW   104        // encoder slab row: [emb 32 | h 64] + pad (208 B)
#define DROW   136        // decoder slab row: 128 bf16 + pad (272 B)
#define RROW   40         // rela row: 32 feat + 8 pad (80 B)
#define SLABE  (16 * EROW * 2)   // 3328 B per encoder slab
#define SLABD  (16 * DROW * 2)   // 4352 B per decoder slab

// ---- LDS layout (byte offsets into one raw pool; phases overlay) ----
#define OFF_RELA   56576
#define OFF_PMAX   97536
#define OFF_ENC    113152
#define OFF_WOP    117504
#define OFF_WIP    118528
#define OFF_BIP    118784
#define OFF_BOP    118912
#define LDS_TOTAL  118928

#define L2E 1.44269504f   // log2(e); gate pre-scales fold the exp-arg mul into W/b

typedef __attribute__((ext_vector_type(8))) short bf16x8;   // 8 bf16 in 4 VGPRs
typedef __attribute__((ext_vector_type(4))) float f32x4;    // MFMA 16x16 C/D frag

__device__ __forceinline__ float lrelu(float x) { return x >= 0.f ? x : 0.1f * x; }
__device__ __forceinline__ float rcpf(float x)  { return __builtin_amdgcn_rcpf(x); }
__device__ __forceinline__ float ex2(float x)   { return __builtin_amdgcn_exp2f(x); }
__device__ __forceinline__ unsigned pk2(float lo, float hi) {
    __hip_bfloat162 p = __float22bfloat162_rn(make_float2(lo, hi));
    unsigned u; __builtin_memcpy(&u, &p, 4); return u;
}
__device__ __forceinline__ bf16x8 mk_frag(float4 f0, float4 f1) {
    uint4 v = { pk2(f0.x, f0.y), pk2(f0.z, f0.w), pk2(f1.x, f1.y), pk2(f1.z, f1.w) };
    bf16x8 r; __builtin_memcpy(&r, &v, 16); return r;
}
__device__ __forceinline__ bf16x8 mk_frag_s(float4 f0, float4 f1, float s) {
    uint4 v = { pk2(f0.x*s, f0.y*s), pk2(f0.z*s, f0.w*s), pk2(f1.x*s, f1.y*s), pk2(f1.z*s, f1.w*s) };
    bf16x8 r; __builtin_memcpy(&r, &v, 16); return r;
}
__device__ __forceinline__ float bf2f(short s) {
    return __uint_as_float(((unsigned)(unsigned short)s) << 16);
}
// Fused LSTM cell update on PRESCALED gates (i,f,o x L2E; g x 2*L2E).
// Products via single-rcp identity: sig(a)*tanh(b) = (1-eb)/((1+ea)(1+eb)).
// 5 exp + 3 rcp per cell. Overflow-safe for |raw gate| < 44.
__device__ __forceinline__ float2 cell_update(float gi, float gf, float gg, float go, float c) {
    float ea = ex2(-gi);
    float ef = ex2(-gf);
    float eb = ex2(-gg);
    float eo = ex2(-go);
    float ff = rcpf(1.f + ef);
    float ig = (1.f - eb) * rcpf((1.f + ea) * (1.f + eb));
    float cc = fmaf(ff, c, ig);
    float ec = ex2(-2.f * L2E * cc);
    float h  = (1.f - ec) * rcpf((1.f + eo) * (1.f + ec));
    return make_float2(h, cc);
}

// ================= fused highwayNet forward: 256 WGs x 512 threads, 16 heroes/WG =================
__global__ __launch_bounds__(512, 2) void highway_fused(
    const float* __restrict__ hist,  const float* __restrict__ nbrs,
    const float* __restrict__ Wip,   const float* __restrict__ bip,
    const float* __restrict__ WihE,  const float* __restrict__ WhhE,
    const float* __restrict__ bihE,  const float* __restrict__ bhhE,
    const float* __restrict__ Wdyn,  const float* __restrict__ bdyn,
    const float* __restrict__ Wnbr,  const float* __restrict__ bnbr,
    const float* __restrict__ WihD,  const float* __restrict__ WhhD,
    const float* __restrict__ bihD,  const float* __restrict__ bhhD,
    const float* __restrict__ Wop,   const float* __restrict__ bop,
    const int*   __restrict__ seg,
    float* __restrict__ fut)                        // [T_OUT][BHERO][2]
{
    __shared__ __align__(16) char lds_raw[LDS_TOTAL];
    auto slab   = (short (*)[16][EROW])  lds_raw;                   // [17][16][EROW]
    auto rela   = (short (*)[RROW])     (lds_raw + OFF_RELA);       // [512][RROW]
    auto pmax   = (float (*)[ENC])      (lds_raw + OFF_PMAX);       // [32][64]
    auto hist_s = (short (*)[16][DROW])  lds_raw;                   // [26][16][DROW]
    auto enc_s  = (float (*)[68])       (lds_raw + OFF_ENC);        // [16][68]
    auto wop_s  = (float (*)[DEC])      (lds_raw + OFF_WOP);        // [2][128]
    auto wip_s  = (float (*)[2])        (lds_raw + OFF_WIP);        // [32][2]
    auto bip_s  = (float*)              (lds_raw + OFF_BIP);        // [32]
    auto bop_s  = (float*)              (lds_raw + OFF_BOP);        // [2]

    const int b0  = blockIdx.x * 16;
    const int n0  = blockIdx.x * 512;               // first neighbor row of this WG
    const int tid = threadIdx.x;
    const int w = tid >> 6, l = tid & 63, r = l & 15, lg = l >> 4;

    // ---------------- P0: consts, zero slab0-h, frag prologues ----------------
    if (tid < EMB) {
        wip_s[tid][0] = Wip[2 * tid];
        wip_s[tid][1] = Wip[2 * tid + 1];
        bip_s[tid]    = bip[tid];
    }
    if (tid < 2 * DEC) wop_s[tid >> 7][tid & 127] = Wop[tid];
    if (tid < 2)       bop_s[tid] = bop[tid];
    for (int i = tid; i < 16 * ENC; i += 512) slab[0][i >> 6][32 + (i & 63)] = 0;

    // encoder B-frags (waves 0-3, prescaled) / nbr B-frags (waves 4-7, unscaled)
    bf16x8 BfE[4][3];
    float  biasE[4];
    bf16x8 BfN[2];
    float  biasn[2] = {0.f, 0.f};
    if (tid < 256) {
        #pragma unroll
        for (int j = 0; j < 4; ++j) {
            const float sj  = (j == 2) ? (2.f * L2E) : L2E;
            const int   col = j * ENC + w * 16 + r;
            biasE[j] = (bihE[col] + bhhE[col]) * sj;
            #pragma unroll
            for (int c = 0; c < 3; ++c) {
                const float* src = (c == 0) ? (WihE + (size_t)col * EMB + 8 * lg)
                                            : (WhhE + (size_t)col * ENC + (c - 1) * 32 + 8 * lg);
                BfE[j][c] = mk_frag_s(*(const float4*)src, *(const float4*)(src + 4), sj);
            }
        }
    } else {
        const int i = w - 4;
        const int ct0 = (i & 1) * 2;
        #pragma unroll
        for (int cc2 = 0; cc2 < 2; ++cc2) {
            const int col = (ct0 + cc2) * 16 + r;
            biasn[cc2] = bnbr[col];
            const float* src = Wnbr + (size_t)col * (2 * T_IN) + 8 * lg;
            BfN[cc2] = mk_frag(*(const float4*)src, *(const float4*)(src + 4));
        }
    }
    __syncthreads();                                // consts + slab0-h ready

    // ---------------- P1: emb prefill (waves 0-3) | rela pair 0 staging (waves 4-7) ----------------
    if (tid < 256) {
        const int t = tid >> 4, m = tid & 15;
        float2 hv = *(const float2*)&hist[((size_t)t * BHERO + b0 + m) * 2];
        #pragma unroll
        for (int jb = 0; jb < 4; ++jb) {
            float e[8];
            #pragma unroll
            for (int q = 0; q < 8; ++q) {
                int j = jb * 8 + q;
                e[q] = lrelu(hv.x * wip_s[j][0] + hv.y * wip_s[j][1] + bip_s[j]);
            }
            uint4 v = { pk2(e[0],e[1]), pk2(e[2],e[3]), pk2(e[4],e[5]), pk2(e[6],e[7]) };
            __builtin_memcpy(&slab[t][m][jb * 8], &v, 16);
        }
    } else {
        const int x = tid - 256;
        const int n  = x & 31;                      // rows 0..31 (pair 0)
        const int ts = x >> 5;                      // 0..7 (also ts+8)
        const int hb = seg[n0 + n];
        float2 h0 = *(const float2*)&hist[((size_t)ts * BHERO + hb) * 2];
        float2 v0 = *(const float2*)&nbrs[((size_t)ts * N_NBR + n0 + n) * 2];
        float2 h1 = *(const float2*)&hist[((size_t)(ts + 8) * BHERO + hb) * 2];
        float2 v1 = *(const float2*)&nbrs[((size_t)(ts + 8) * N_NBR + n0 + n) * 2];
        unsigned* dst = (unsigned*)&rela[n][0];
        dst[ts]     = pk2(h0.x - v0.x, h0.y - v0.y);
        dst[ts + 8] = pk2(h1.x - v1.x, h1.y - v1.y);
    }
    f32x4 cstE = {0.f, 0.f, 0.f, 0.f};              // cell state: hero 4*lg+q, unit w*16+r
    __syncthreads();                                // emb + rela pair 0 ready

    // ---------------- P2: encoder LSTM (waves 0-3) || nbr stage+GEMM pipeline (waves 4-7) ----------------
    {
        const char* rbase = lds_raw + (size_t)r * (EROW * 2);
        char*       wbase = lds_raw + SLABE + (size_t)(4 * lg) * (EROW * 2) + (size_t)(32 + w * 16 + r) * 2;
        const int   x = tid - 256;                  // valid for waves 4-7
        #pragma unroll 1
        for (int t = 0; t < T_IN; ++t) {
            if (tid < 256) {
                const short* rp = (const short*)rbase;
                bf16x8 a0 = *(const bf16x8*)(rp + (0 + lg) * 8);
                bf16x8 a1 = *(const bf16x8*)(rp + (4 + lg) * 8);
                bf16x8 a2 = *(const bf16x8*)(rp + (8 + lg) * 8);
                f32x4 acc[4];
                #pragma unroll
                for (int j = 0; j < 4; ++j) {
                    f32x4 aA = (f32x4){biasE[j], biasE[j], biasE[j], biasE[j]};
                    f32x4 aB = (f32x4){0.f, 0.f, 0.f, 0.f};
                    aA = __builtin_amdgcn_mfma_f32_16x16x32_bf16(a0, BfE[j][0], aA, 0, 0, 0);
                    aB = __builtin_amdgcn_mfma_f32_16x16x32_bf16(a1, BfE[j][1], aB, 0, 0, 0);
                    aA = __builtin_amdgcn_mfma_f32_16x16x32_bf16(a2, BfE[j][2], aA, 0, 0, 0);
                    acc[j] = aA + aB;
                }
                float hq[4];
                #pragma unroll
                for (int q = 0; q < 4; ++q) {
                    float2 hc = cell_update(acc[0][q], acc[1][q], acc[2][q], acc[3][q], cstE[q]);
                    hq[q]   = hc.x;
                    cstE[q] = hc.y;
                }
                unsigned u01 = pk2(hq[0], hq[1]), u23 = pk2(hq[2], hq[3]);
                short* wp = (short*)wbase;
                wp[0 * EROW] = (short)u01; wp[1 * EROW] = (short)(u01 >> 16);
                wp[2 * EROW] = (short)u23; wp[3 * EROW] = (short)(u23 >> 16);
            } else {
                // stage pair t+1 (rows 32(t+1)..+31)
                if (t < T_IN - 1) {
                    const int n  = 32 * (t + 1) + (x & 31);
                    const int ts = x >> 5;
                    const int hb = seg[n0 + n];
                    float2 h0 = *(const float2*)&hist[((size_t)ts * BHERO + hb) * 2];
                    float2 v0 = *(const float2*)&nbrs[((size_t)ts * N_NBR + n0 + n) * 2];
                    float2 h1 = *(const float2*)&hist[((size_t)(ts + 8) * BHERO + hb) * 2];
                    float2 v1 = *(const float2*)&nbrs[((size_t)(ts + 8) * N_NBR + n0 + n) * 2];
                    unsigned* dst = (unsigned*)&rela[n][0];
                    dst[ts]     = pk2(h0.x - v0.x, h0.y - v0.y);
                    dst[ts + 8] = pk2(h1.x - v1.x, h1.y - v1.y);
                }
                // GEMM pair t (staged last iteration): wave i covers rt = 2t + (i>>1), 2 col-tiles
                const int i  = w - 4;
                const int rt = 2 * t + (i >> 1);
                const int ct0 = (i & 1) * 2;
                bf16x8 a = *(const bf16x8*)&rela[rt * 16 + r][8 * lg];
                #pragma unroll
                for (int cc2 = 0; cc2 < 2; ++cc2) {
                    f32x4 acc = {biasn[cc2], biasn[cc2], biasn[cc2], biasn[cc2]};
                    acc = __builtin_amdgcn_mfma_f32_16x16x32_bf16(a, BfN[cc2], acc, 0, 0, 0);
                    float m4 = fmaxf(fmaxf(acc[0], acc[1]), fmaxf(acc[2], acc[3]));
                    m4 = fmaxf(m4, __shfl_xor(m4, 16));
                    m4 = fmaxf(m4, __shfl_xor(m4, 32));
                    if (l < 16) pmax[rt][(ct0 + cc2) * 16 + r] = m4;
                }
            }
            __syncthreads();                        // h(t) + pair-(t+1) rela + pair-t pmax ready
            rbase += SLABE; wbase += SLABE;
        }
    }

    // ---------------- P3: enc_s = [hist_e | scene_d], zero decoder slab 0 ----------------
    #pragma unroll
    for (int it = 0; it < 2; ++it) {
        const int s = tid + 512 * it;               // 1024 tasks: (m, col)
        const int m = s >> 6, col = s & 63;
        const float* wd = Wdyn + (size_t)(col & 31) * ENC;
        float a = bdyn[col & 31];
        if (col < 32) {
            const short* hp = &slab[T_IN][m][32];
            #pragma unroll
            for (int kb = 0; kb < 8; ++kb) {
                bf16x8 hv = *(const bf16x8*)(hp + kb * 8);
                #pragma unroll
                for (int e = 0; e < 8; ++e)
                    a = fmaf(bf2f(hv[e]), wd[kb * 8 + e], a);
            }
        } else {
            #pragma unroll
            for (int kb = 0; kb < 16; ++kb) {
                float4 p0 = *(const float4*)&pmax[2 * m][kb * 4];
                float4 p1 = *(const float4*)&pmax[2 * m + 1][kb * 4];
                a = fmaf(lrelu(fmaxf(p0.x, p1.x)), wd[kb * 4 + 0], a);
                a = fmaf(lrelu(fmaxf(p0.y, p1.y)), wd[kb * 4 + 1], a);
                a = fmaf(lrelu(fmaxf(p0.z, p1.z)), wd[kb * 4 + 2], a);
                a = fmaf(lrelu(fmaxf(p0.w, p1.w)), wd[kb * 4 + 3], a);
            }
        }
        enc_s[m][col] = lrelu(a);
    }
    for (int i = tid; i < 16 * DROW; i += 512) ((short*)hist_s)[i] = 0;   // zero h(0)
    __syncthreads();                                // enc_s + decoder slab0 ready

    // ---------------- P4: decoder frags (prescaled) + xw prologue + 25-step LSTM ----------------
    const int u0 = w * 16;
    bf16x8 BfD[4][4];
    float  biasD[4];
    float  sjD[4];
    #pragma unroll
    for (int j = 0; j < 4; ++j) {
        const float sj  = (j == 2) ? (2.f * L2E) : L2E;
        const int   col = j * DEC + u0 + r;
        sjD[j]   = sj;
        biasD[j] = (bihD[col] + bhhD[col]) * sj;
        #pragma unroll
        for (int c = 0; c < 4; ++c) {
            const float* src = WhhD + (size_t)col * DEC + c * 32 + 8 * lg;
            BfD[j][c] = mk_frag_s(*(const float4*)src, *(const float4*)(src + 4), sj);
        }
    }
    f32x4 xwf[4];
    {
        bf16x8 aE[2];
        #pragma unroll
        for (int c = 0; c < 2; ++c) {
            float4 f0 = *(const float4*)&enc_s[r][c * 32 + 8 * lg];
            float4 f1 = *(const float4*)&enc_s[r][c * 32 + 8 * lg + 4];
            aE[c] = mk_frag(f0, f1);
        }
        #pragma unroll
        for (int j = 0; j < 4; ++j) {
            const int col = j * DEC + u0 + r;
            f32x4 a = {biasD[j], biasD[j], biasD[j], biasD[j]};
            #pragma unroll
            for (int c = 0; c < 2; ++c) {
                const float* src = WihD + (size_t)col * (2 * DYN) + c * 32 + 8 * lg;
                a = __builtin_amdgcn_mfma_f32_16x16x32_bf16(
                        aE[c], mk_frag_s(*(const float4*)src, *(const float4*)(src + 4), sjD[j]),
                        a, 0, 0, 0);
            }
            xwf[j] = a;
        }
    }

    f32x4 cst = {0.f, 0.f, 0.f, 0.f};
    {
        const char* rbase = lds_raw + (size_t)r * (DROW * 2);
        char*       wbase = lds_raw + SLABD + (size_t)(4 * lg) * (DROW * 2) + (size_t)(u0 + r) * 2;
        #pragma unroll 1
        for (int t = 0; t < T_OUT; ++t) {
            const short* rp = (const short*)rbase;
            bf16x8 a_[4];
            #pragma unroll
            for (int c = 0; c < 4; ++c)
                a_[c] = *(const bf16x8*)(rp + (4 * c + lg) * 8);
            f32x4 acc[4];
            #pragma unroll
            for (int j = 0; j < 4; ++j) {
                f32x4 aA = xwf[j];
                f32x4 aB = (f32x4){0.f, 0.f, 0.f, 0.f};
                aA = __builtin_amdgcn_mfma_f32_16x16x32_bf16(a_[0], BfD[j][0], aA, 0, 0, 0);
                aB = __builtin_amdgcn_mfma_f32_16x16x32_bf16(a_[1], BfD[j][1], aB, 0, 0, 0);
                aA = __builtin_amdgcn_mfma_f32_16x16x32_bf16(a_[2], BfD[j][2], aA, 0, 0, 0);
                aB = __builtin_amdgcn_mfma_f32_16x16x32_bf16(a_[3], BfD[j][3], aB, 0, 0, 0);
                acc[j] = aA + aB;
            }
            float hq[4];
            #pragma unroll
            for (int q = 0; q < 4; ++q) {
                float2 hc = cell_update(acc[0][q], acc[1][q], acc[2][q], acc[3][q], cst[q]);
                hq[q]  = hc.x;
                cst[q] = hc.y;
            }
            unsigned u01 = pk2(hq[0], hq[1]), u23 = pk2(hq[2], hq[3]);
            short* wp = (short*)wbase;
            wp[0 * DROW] = (short)u01; wp[1 * DROW] = (short)(u01 >> 16);
            wp[2 * DROW] = (short)u23; wp[3 * DROW] = (short)(u23 >> 16);
            __syncthreads();                        // h(t) ready (slab t+1 was unread)
            rbase += SLABD; wbase += SLABD;
        }
    }

    // ---------------- P5: output head via MFMA ----------------
    // Per t: fut[t] = h(t) [16x128] @ Wop^T [128x2(pad16)] + bop. Wave w: t = w, w+8, ...
    {
        bf16x8 Bop[4];
        #pragma unroll
        for (int c = 0; c < 4; ++c) {
            float wv[8];
            #pragma unroll
            for (int e = 0; e < 8; ++e)
                wv[e] = (r < 2) ? wop_s[r][c * 32 + 8 * lg + e] : 0.f;
            uint4 v = { pk2(wv[0],wv[1]), pk2(wv[2],wv[3]), pk2(wv[4],wv[5]), pk2(wv[6],wv[7]) };
            __builtin_memcpy(&Bop[c], &v, 16);
        }
        const float bopr = (r < 2) ? bop_s[r] : 0.f;
        #pragma unroll 1
        for (int t = w; t < T_OUT; t += 8) {
            const short* rp = &hist_s[t + 1][r][0];
            bf16x8 a_[4];
            #pragma unroll
            for (int c = 0; c < 4; ++c)
                a_[c] = *(const bf16x8*)(rp + (4 * c + lg) * 8);
            f32x4 acc = {0.f, 0.f, 0.f, 0.f};
            #pragma unroll
            for (int c = 0; c < 4; ++c)
                acc = __builtin_amdgcn_mfma_f32_16x16x32_bf16(a_[c], Bop[c], acc, 0, 0, 0);
            if (r < 2) {
                #pragma unroll
                for (int q = 0; q < 4; ++q)
                    fut[((size_t)t * BHERO + b0 + 4 * lg + q) * 2 + r] = acc[q] + bopr;
            }
        }
    }
}

extern "C" void kernel_launch(void* const* d_in, const int* in_sizes, int n_in,
                              void* d_out, int out_size, void* d_ws, size_t ws_size,
                              hipStream_t stream) {
    (void)d_ws; (void)ws_size; (void)in_sizes; (void)n_in; (void)out_size;
    const float* hist  = (const float*)d_in[0];
    const float* nbrs  = (const float*)d_in[1];
    const float* Wip   = (const float*)d_in[2];
    const float* bip   = (const float*)d_in[3];
    const float* Wih_e = (const float*)d_in[4];
    const float* Whh_e = (const float*)d_in[5];
    const float* bih_e = (const float*)d_in[6];
    const float* bhh_e = (const float*)d_in[7];
    const float* Wdyn  = (const float*)d_in[8];
    const float* bdyn  = (const float*)d_in[9];
    const float* Wnbr  = (const float*)d_in[10];
    const float* bnbr  = (const float*)d_in[11];
    const float* Wih_d = (const float*)d_in[12];
    const float* Whh_d = (const float*)d_in[13];
    const float* bih_d = (const float*)d_in[14];
    const float* bhh_d = (const float*)d_in[15];
    const float* Wop   = (const float*)d_in[16];
    const float* bop   = (const float*)d_in[17];
    const int*   seg   = (const int*)d_in[18];
    float* fut = (float*)d_out;

    hipLaunchKernelGGL(highway_fused, dim3(BHERO / 16), dim3(512), 0, stream,
                       hist, nbrs, Wip, bip, Wih_e, Whh_e, bih_e, bhh_e, Wdyn, bdyn,
                       Wnbr, bnbr, Wih_d, Whh_d, bih_d, bhh_d, Wop, bop, seg, fut);
}